// Round 6
// baseline (437.052 us; speedup 1.0000x reference)
//
#include <hip/hip_runtime.h>

#define N_NODES_C   50000
#define N_EDGES_C   1600000
#define FEAT        128
#define NREL        8
#define NBUCKETS    400000
#define KTOT        1024
#define TILE        16                 // nodes per block; 50000 = 3125*16 exactly

// ---------------- workspace layout (bytes) ----------------
#define WS_COUNTS   0          // u32[100000] (u8x4 packed)     400,000
#define WS_OFFSETS  400000     // u32[400001] (+sentinel)     1,600,016
#define WS_RANK     2000016    // u8[1.6M]                    1,600,000
#define WS_BSUM     3600016    // u32[512]                        2,048
#define WS_BOFF     3602064    // u32[512]                        2,048
#define WS_SORTED   3604112    // u32[1.6M]                   6,400,000
#define WS_HB       10004112   // bf16[50000*128]            12,800,000
#define WS_WT       22804112   // bf16[128][1024]               262,144
#define WS_NEEDED   23066256

typedef __attribute__((ext_vector_type(8))) short bf16x8;
typedef __attribute__((ext_vector_type(4))) float f32x4;

__device__ __forceinline__ unsigned short f2bf(float f) {
    unsigned u = __float_as_uint(f);
    return (unsigned short)((u + 0x7fffu + ((u >> 16) & 1u)) >> 16);  // RNE
}
__device__ __forceinline__ float bf2f(unsigned short b) {
    return __uint_as_float((unsigned)b << 16);
}
__device__ __forceinline__ float lo16(unsigned u) { return __uint_as_float(u << 16); }
__device__ __forceinline__ float hi16(unsigned u) { return __uint_as_float(u & 0xffff0000u); }

// fused: cast h->bf16 | zero packed counts | build Wcat^T bf16 [n][r*128+k]
__global__ void k_prep(const float* __restrict__ h, const float* __restrict__ W,
                       unsigned* __restrict__ counts, unsigned short* __restrict__ hb,
                       unsigned short* __restrict__ wt) {
    int b = blockIdx.x, t = threadIdx.x;
    if (b < 3125) {                         // h cast: 6.4M elems, 8/thread
        int i = (b * 256 + t) * 8;
        float4 v0 = *(const float4*)&h[i];
        float4 v1 = *(const float4*)&h[i + 4];
        uint4 o;
        o.x = (unsigned)f2bf(v0.x) | ((unsigned)f2bf(v0.y) << 16);
        o.y = (unsigned)f2bf(v0.z) | ((unsigned)f2bf(v0.w) << 16);
        o.z = (unsigned)f2bf(v1.x) | ((unsigned)f2bf(v1.y) << 16);
        o.w = (unsigned)f2bf(v1.z) | ((unsigned)f2bf(v1.w) << 16);
        *(uint4*)&hb[i] = o;
    } else if (b < 3125 + 98) {             // zero 100000 u32 of packed counts
        int i = (b - 3125) * 256 + t;       // uint4 index
        if (i < 25000) ((uint4*)counts)[i] = make_uint4(0u, 0u, 0u, 0u);
    } else {                                // wt[n*1024 + rk] = W[rk*128 + n]
        int i = (b - 3223) * 256 + t;       // 0..131071
        int n = i >> 10, rk = i & 1023;
        wt[i] = f2bf(W[rk * FEAT + n]);
    }
}

// packed u8 histogram: 4 buckets per u32 word (bucket count << 255 w.h.p.)
__global__ void k_hist(const int* __restrict__ dst, const int* __restrict__ et,
                       unsigned* __restrict__ counts, unsigned char* __restrict__ rank) {
    int e = blockIdx.x * 256 + threadIdx.x;
    if (e < N_EDGES_C) {
        int key = dst[e] * NREL + et[e];
        int sh = 8 * (key & 3);
        unsigned old = atomicAdd(&counts[key >> 2], 1u << sh);
        rank[e] = (unsigned char)((old >> sh) & 0xffu);
    }
}

__global__ void k_scan_a(const unsigned* __restrict__ counts, unsigned* __restrict__ bsum) {
    __shared__ unsigned s[1024];
    int t = threadIdx.x;
    int i = blockIdx.x * 1024 + t;
    unsigned v = 0;
    if (i < NBUCKETS) v = (counts[i >> 2] >> (8 * (i & 3))) & 0xffu;
    s[t] = v;
    __syncthreads();
    for (int o = 512; o > 0; o >>= 1) {
        if (t < o) s[t] += s[t + o];
        __syncthreads();
    }
    if (t == 0) bsum[blockIdx.x] = s[0];
}

__global__ void k_scan_b(const unsigned* __restrict__ bsum, unsigned* __restrict__ boff, int nb) {
    __shared__ unsigned s[512];
    int t = threadIdx.x;
    unsigned v = (t < nb) ? bsum[t] : 0u;
    s[t] = v;
    __syncthreads();
    for (int o = 1; o < 512; o <<= 1) {
        unsigned u = (t >= o) ? s[t - o] : 0u;
        __syncthreads();
        s[t] += u;
        __syncthreads();
    }
    if (t < nb) boff[t] = s[t] - v;
}

__global__ void k_scan_c(const unsigned* __restrict__ counts, const unsigned* __restrict__ boff,
                         unsigned* __restrict__ offsets) {
    __shared__ unsigned s[1024];
    int t = threadIdx.x;
    int i = blockIdx.x * 1024 + t;
    unsigned v = 0;
    if (i < NBUCKETS) v = (counts[i >> 2] >> (8 * (i & 3))) & 0xffu;
    s[t] = v;
    __syncthreads();
    for (int o = 1; o < 1024; o <<= 1) {
        unsigned u = (t >= o) ? s[t - o] : 0u;
        __syncthreads();
        s[t] += u;
        __syncthreads();
    }
    if (i < NBUCKETS) offsets[i] = boff[blockIdx.x] + s[t] - v;
    if (i == NBUCKETS) offsets[i] = N_EDGES_C;   // sentinel
}

// XCD-partitioned scatter: block handles key range [(bid&7)*50000, +50000)
// over a contiguous edge chunk -> each 64B line of `sorted` is written from
// exactly one XCD (round-robin bid->XCD), so lines stay in that L2.
__global__ void k_scatter(const int* __restrict__ src, const int* __restrict__ dst,
                          const int* __restrict__ et, const float* __restrict__ norm,
                          const unsigned* __restrict__ offsets,
                          const unsigned char* __restrict__ rank,
                          unsigned* __restrict__ sorted) {
    int xcd = blockIdx.x & 7;
    int blk = blockIdx.x >> 3;                 // 0..781
    int keyLo = xcd * (NBUCKETS / 8);
    int keyHi = keyLo + (NBUCKETS / 8);
    int e0 = blk * 2048;
    int e1 = e0 + 2048; if (e1 > N_EDGES_C) e1 = N_EDGES_C;
    for (int e = e0 + threadIdx.x; e < e1; e += 256) {
        int key = dst[e] * NREL + et[e];
        if (key >= keyLo && key < keyHi) {
            unsigned pos = offsets[key] + (unsigned)rank[e];
            sorted[pos] = ((unsigned)src[e] << 16) | (unsigned)f2bf(norm[e]);
        }
    }
}

// Fused aggregate+GEMM, 16 nodes/block. Wave w streams rows w*4..w*4+3 as 4
// concurrent slots (row = 8 contiguous rel-buckets in `sorted`), next-record
// prefetched, accumulating all relations into one [16][1024] swizzled LDS
// X-tile. ONE barrier, then a single K=1024 MFMA pass (B from L2-resident wt).
__global__ __launch_bounds__(256) void k_fused(const unsigned* __restrict__ sorted,
                                               const unsigned* __restrict__ offsets,
                                               const unsigned short* __restrict__ hb,
                                               const unsigned short* __restrict__ wt,
                                               const float* __restrict__ bias,
                                               float* __restrict__ out) {
    __shared__ char At[32768];            // [16 rows][1024 k] bf16, row-XOR swizzle
    __shared__ float csLds[TILE][NREL];
    int t = threadIdx.x, w = t >> 6, lane = t & 63;
    int node0 = blockIdx.x * TILE;
    int grp = lane >> 4, ln16 = lane & 15;

    // 33 bucket boundaries for this wave's 4 rows (8 rels each)
    int kbase = (node0 + w * 4) * NREL;
    unsigned myofs = offsets[kbase + (lane < 33 ? lane : 32)];

    float a0[4], a1[4], cs[4];
    unsigned p[4], bend[4], rec[4];
    int j[4];
    bool live[4];

#pragma unroll
    for (int s = 0; s < 4; s++) {
        int row = w * 4 + s;
        a0[s] = a1[s] = cs[s] = 0.f;
        p[s] = __shfl(myofs, s * 8);
        j[s] = 0;
        while (j[s] < 8) {                // skip leading empty buckets (flush 0)
            bend[s] = __shfl(myofs, s * 8 + j[s] + 1);
            if (p[s] < bend[s]) break;
            *(unsigned*)(At + ((row * 2048 + j[s] * 256 + lane * 4) ^ ((row & 7) << 4))) = 0u;
            if (lane == 0) csLds[row][j[s]] = 0.f;
            j[s]++;
        }
        live[s] = (j[s] < 8);
        rec[s] = live[s] ? sorted[p[s]] : 0u;
    }

    while (live[0] | live[1] | live[2] | live[3]) {
#pragma unroll
        for (int s = 0; s < 4; s++) {
            if (!live[s]) continue;
            int row = w * 4 + s;
            unsigned rc = rec[s];
            p[s]++;
            unsigned pn = (p[s] < N_EDGES_C) ? p[s] : (N_EDGES_C - 1);
            unsigned recn = sorted[pn];    // prefetch next (indep of gather below)
            float nv = bf2f((unsigned short)(rc & 0xffffu));
            unsigned hv = *(const unsigned*)&hb[(size_t)(rc >> 16) * FEAT + lane * 2];
            a0[s] += nv * lo16(hv);
            a1[s] += nv * hi16(hv);
            cs[s] += nv;
            rec[s] = recn;
            if (p[s] >= bend[s]) {         // bucket done: flush, advance (skip empties)
                *(unsigned*)(At + ((row * 2048 + j[s] * 256 + lane * 4) ^ ((row & 7) << 4))) =
                    (unsigned)f2bf(a0[s]) | ((unsigned)f2bf(a1[s]) << 16);
                if (lane == 0) csLds[row][j[s]] = cs[s];
                a0[s] = a1[s] = cs[s] = 0.f;
                j[s]++;
                while (j[s] < 8) {
                    bend[s] = __shfl(myofs, s * 8 + j[s] + 1);
                    if (p[s] < bend[s]) break;
                    *(unsigned*)(At + ((row * 2048 + j[s] * 256 + lane * 4) ^ ((row & 7) << 4))) = 0u;
                    if (lane == 0) csLds[row][j[s]] = 0.f;
                    j[s]++;
                }
                live[s] = (j[s] < 8);
            }
        }
    }
    __syncthreads();

    // ---- single MFMA pass: K=1024, wave covers 2 col-tiles ----
    f32x4 acc[2];
    acc[0] = (f32x4){0.f, 0.f, 0.f, 0.f};
    acc[1] = (f32x4){0.f, 0.f, 0.f, 0.f};
#pragma unroll 8
    for (int ks = 0; ks < 32; ks++) {
        bf16x8 af = *(const bf16x8*)(At + ((ln16 * 2048 + ks * 64 + grp * 16) ^ ((ln16 & 7) << 4)));
#pragma unroll
        for (int c = 0; c < 2; c++) {
            int ncol = (w * 2 + c) * 16 + ln16;
            bf16x8 bf = *(const bf16x8*)(wt + (size_t)ncol * KTOT + ks * 32 + grp * 8);
            acc[c] = __builtin_amdgcn_mfma_f32_16x16x32_bf16(af, bf, acc[c], 0, 0, 0);
        }
    }

    // ---- epilogue: bias via csum + ReLU. D map: col=lane&15, row=(lane>>4)*4+reg
#pragma unroll
    for (int i = 0; i < 4; i++) {
        int rl = grp * 4 + i;
        int g  = node0 + rl;
        float csv[NREL];
#pragma unroll
        for (int rr = 0; rr < NREL; rr++) csv[rr] = csLds[rl][rr];
#pragma unroll
        for (int c = 0; c < 2; c++) {
            int col = (w * 2 + c) * 16 + ln16;
            float v = acc[c][i];
#pragma unroll
            for (int rr = 0; rr < NREL; rr++) v += csv[rr] * bias[rr * FEAT + col];
            out[(size_t)g * FEAT + col] = fmaxf(v, 0.f);
        }
    }
}

extern "C" void kernel_launch(void* const* d_in, const int* in_sizes, int n_in,
                              void* d_out, int out_size, void* d_ws, size_t ws_size,
                              hipStream_t stream) {
    const float* h    = (const float*)d_in[0];
    const int*   src  = (const int*)d_in[1];
    const int*   dst  = (const int*)d_in[2];
    const int*   et   = (const int*)d_in[3];
    const float* norm = (const float*)d_in[4];
    const float* W    = (const float*)d_in[5];
    const float* b    = (const float*)d_in[6];
    float*       out  = (float*)d_out;

    if (ws_size < (size_t)WS_NEEDED) return;

    char* ws = (char*)d_ws;
    unsigned*       counts  = (unsigned*)(ws + WS_COUNTS);
    unsigned*       offsets = (unsigned*)(ws + WS_OFFSETS);
    unsigned char*  rank    = (unsigned char*)(ws + WS_RANK);
    unsigned*       bsum    = (unsigned*)(ws + WS_BSUM);
    unsigned*       boff    = (unsigned*)(ws + WS_BOFF);
    unsigned*       sorted  = (unsigned*)(ws + WS_SORTED);
    unsigned short* hb      = (unsigned short*)(ws + WS_HB);
    unsigned short* wt      = (unsigned short*)(ws + WS_WT);

    int nb = (NBUCKETS + 1023) / 1024;   // 391

    k_prep<<<3125 + 98 + 512, 256, 0, stream>>>(h, W, counts, hb, wt);
    k_hist<<<6250, 256, 0, stream>>>(dst, et, counts, rank);
    k_scan_a<<<nb, 1024, 0, stream>>>(counts, bsum);
    k_scan_b<<<1, 512, 0, stream>>>(bsum, boff, nb);
    k_scan_c<<<nb, 1024, 0, stream>>>(counts, boff, offsets);
    k_scatter<<<8 * 782, 256, 0, stream>>>(src, dst, et, norm, offsets, rank, sorted);

    k_fused<<<N_NODES_C / TILE, 256, 0, stream>>>(sorted, offsets, hb, wt, b, out);
}

// Round 7
// 316.218 us; speedup vs baseline: 1.3821x; 1.3821x over previous
//
#include <hip/hip_runtime.h>

#define N_NODES_C   50000
#define N_EDGES_C   1600000
#define FEAT        128
#define NREL        8
#define NBUCKETS    400000
#define KTOT        1024
#define TILE        16                 // nodes per block; 50000 = 3125*16 exactly

// ---------------- workspace layout (bytes) ----------------
#define WS_COUNTS   0          // u32[100000] (u8x4 packed)     400,000
#define WS_OFFSETS  400000     // u32[400001] (+sentinel)     1,600,016
#define WS_RANK     2000016    // u8[1.6M]                    1,600,000
#define WS_BSUM     3600016    // u32[512]                        2,048
#define WS_BOFF     3602064    // u32[512]                        2,048
#define WS_SORTED   3604112    // u32[1.6M]                   6,400,000
#define WS_HB       10004112   // bf16[50000*128]            12,800,000
#define WS_WT       22804112   // bf16[128][1024]               262,144
#define WS_NEEDED   23066256

typedef __attribute__((ext_vector_type(8))) short bf16x8;
typedef __attribute__((ext_vector_type(4))) float f32x4;

__device__ __forceinline__ unsigned short f2bf(float f) {
    unsigned u = __float_as_uint(f);
    return (unsigned short)((u + 0x7fffu + ((u >> 16) & 1u)) >> 16);  // RNE
}
__device__ __forceinline__ float bf2f(unsigned short b) {
    return __uint_as_float((unsigned)b << 16);
}
__device__ __forceinline__ float lo16(unsigned u) { return __uint_as_float(u << 16); }
__device__ __forceinline__ float hi16(unsigned u) { return __uint_as_float(u & 0xffff0000u); }

// fused: cast h->bf16 | zero packed counts | build Wcat^T bf16 [n][r*128+k]
__global__ void k_prep(const float* __restrict__ h, const float* __restrict__ W,
                       unsigned* __restrict__ counts, unsigned short* __restrict__ hb,
                       unsigned short* __restrict__ wt) {
    int b = blockIdx.x, t = threadIdx.x;
    if (b < 3125) {                         // h cast: 6.4M elems, 8/thread
        int i = (b * 256 + t) * 8;
        float4 v0 = *(const float4*)&h[i];
        float4 v1 = *(const float4*)&h[i + 4];
        uint4 o;
        o.x = (unsigned)f2bf(v0.x) | ((unsigned)f2bf(v0.y) << 16);
        o.y = (unsigned)f2bf(v0.z) | ((unsigned)f2bf(v0.w) << 16);
        o.z = (unsigned)f2bf(v1.x) | ((unsigned)f2bf(v1.y) << 16);
        o.w = (unsigned)f2bf(v1.z) | ((unsigned)f2bf(v1.w) << 16);
        *(uint4*)&hb[i] = o;
    } else if (b < 3125 + 98) {             // zero 100000 u32 of packed counts
        int i = (b - 3125) * 256 + t;       // uint4 index
        if (i < 25000) ((uint4*)counts)[i] = make_uint4(0u, 0u, 0u, 0u);
    } else {                                // wt[n*1024 + rk] = W[rk*128 + n]
        int i = (b - 3223) * 256 + t;       // 0..131071
        int n = i >> 10, rk = i & 1023;
        wt[i] = f2bf(W[rk * FEAT + n]);
    }
}

// packed u8 histogram: 4 buckets per u32 word (bucket count << 255 w.h.p.)
__global__ void k_hist(const int* __restrict__ dst, const int* __restrict__ et,
                       unsigned* __restrict__ counts, unsigned char* __restrict__ rank) {
    int e = blockIdx.x * 256 + threadIdx.x;
    if (e < N_EDGES_C) {
        int key = dst[e] * NREL + et[e];
        int sh = 8 * (key & 3);
        unsigned old = atomicAdd(&counts[key >> 2], 1u << sh);
        rank[e] = (unsigned char)((old >> sh) & 0xffu);
    }
}

__global__ void k_scan_a(const unsigned* __restrict__ counts, unsigned* __restrict__ bsum) {
    __shared__ unsigned s[1024];
    int t = threadIdx.x;
    int i = blockIdx.x * 1024 + t;
    unsigned v = 0;
    if (i < NBUCKETS) v = (counts[i >> 2] >> (8 * (i & 3))) & 0xffu;
    s[t] = v;
    __syncthreads();
    for (int o = 512; o > 0; o >>= 1) {
        if (t < o) s[t] += s[t + o];
        __syncthreads();
    }
    if (t == 0) bsum[blockIdx.x] = s[0];
}

__global__ void k_scan_b(const unsigned* __restrict__ bsum, unsigned* __restrict__ boff, int nb) {
    __shared__ unsigned s[512];
    int t = threadIdx.x;
    unsigned v = (t < nb) ? bsum[t] : 0u;
    s[t] = v;
    __syncthreads();
    for (int o = 1; o < 512; o <<= 1) {
        unsigned u = (t >= o) ? s[t - o] : 0u;
        __syncthreads();
        s[t] += u;
        __syncthreads();
    }
    if (t < nb) boff[t] = s[t] - v;
}

__global__ void k_scan_c(const unsigned* __restrict__ counts, const unsigned* __restrict__ boff,
                         unsigned* __restrict__ offsets) {
    __shared__ unsigned s[1024];
    int t = threadIdx.x;
    int i = blockIdx.x * 1024 + t;
    unsigned v = 0;
    if (i < NBUCKETS) v = (counts[i >> 2] >> (8 * (i & 3))) & 0xffu;
    s[t] = v;
    __syncthreads();
    for (int o = 1; o < 1024; o <<= 1) {
        unsigned u = (t >= o) ? s[t - o] : 0u;
        __syncthreads();
        s[t] += u;
        __syncthreads();
    }
    if (i < NBUCKETS) offsets[i] = boff[blockIdx.x] + s[t] - v;
    if (i == NBUCKETS) offsets[i] = N_EDGES_C;   // sentinel
}

// atomic-free scatter (plain R4 form — XCD partitioning hurt, reverted)
__global__ void k_scatter(const int* __restrict__ src, const int* __restrict__ dst,
                          const int* __restrict__ et, const float* __restrict__ norm,
                          const unsigned* __restrict__ offsets,
                          const unsigned char* __restrict__ rank,
                          unsigned* __restrict__ sorted) {
    int e = blockIdx.x * 256 + threadIdx.x;
    if (e < N_EDGES_C) {
        int key = dst[e] * NREL + et[e];
        unsigned pos = offsets[key] + (unsigned)rank[e];
        sorted[pos] = ((unsigned)src[e] << 16) | (unsigned)f2bf(norm[e]);
    }
}

// Fused aggregate+GEMM, TILE=16 nodes/block, 512 threads = 8 waves.
// LDS 32KB + 512 thr -> exactly 4 blocks/CU = 32 waves/CU (100% cap).
// Wave w owns rows 2w, 2w+1: each row = ONE contiguous record stream in
// `sorted` (its 8 rel-buckets are adjacent). Two streams per wave, per-record
// next-rec prefetch -> 4 memory ops in flight. All stream state (p/bend/j)
// is wave-uniform -> scalar branches only. No barriers during aggregation.
// Then one barrier + single K=1024 MFMA pass (1 col-tile/wave, B from wt).
__global__ __launch_bounds__(512) void k_fused(const unsigned* __restrict__ sorted,
                                               const unsigned* __restrict__ offsets,
                                               const unsigned short* __restrict__ hb,
                                               const unsigned short* __restrict__ wt,
                                               const float* __restrict__ bias,
                                               float* __restrict__ out) {
    __shared__ char At[32768];            // [16 rows][1024 k] bf16, XOR-swizzled
    __shared__ float csLds[TILE][NREL];
    int t = threadIdx.x, w = t >> 6, lane = t & 63;
    int node0 = blockIdx.x * TILE;
    int grp = lane >> 4, ln16 = lane & 15;
    int row0 = 2 * w, row1 = 2 * w + 1;

    // 9 bucket boundaries per row, held lane-parallel (lane i -> offsets[n*8+i])
    unsigned bnds0 = offsets[(node0 + row0) * NREL + (lane <= 8 ? lane : 8)];
    unsigned bnds1 = offsets[(node0 + row1) * NREL + (lane <= 8 ? lane : 8)];

    // flush helpers: write acc for (row, bucket j) into swizzled LDS column
#define FLUSH(ROW, J, A0, A1, CS)                                                  \
    do {                                                                           \
        *(unsigned*)(At + (ROW) * 2048 +                                           \
                     (((J) * 256 + lane * 4) ^ (((ROW) & 7) << 4))) =              \
            (unsigned)f2bf(A0) | ((unsigned)f2bf(A1) << 16);                       \
        if (lane == 0) csLds[ROW][J] = (CS);                                       \
    } while (0)

    // ---- stream init (skip leading empty buckets, flushing zeros) ----
    unsigned p0 = __shfl(bnds0, 0), p1 = __shfl(bnds1, 0);
    int j0 = 0, j1 = 0;
    unsigned bend0 = __shfl(bnds0, 1), bend1 = __shfl(bnds1, 1);
    while (j0 < 8 && p0 >= bend0) {
        FLUSH(row0, j0, 0.f, 0.f, 0.f);
        j0++; if (j0 < 8) bend0 = __shfl(bnds0, j0 + 1);
    }
    while (j1 < 8 && p1 >= bend1) {
        FLUSH(row1, j1, 0.f, 0.f, 0.f);
        j1++; if (j1 < 8) bend1 = __shfl(bnds1, j1 + 1);
    }
    bool live0 = (j0 < 8), live1 = (j1 < 8);
    unsigned rec0 = sorted[live0 ? p0 : 0];
    unsigned rec1 = sorted[live1 ? p1 : 0];
    float a00 = 0.f, a01 = 0.f, cs0 = 0.f;
    float a10 = 0.f, a11 = 0.f, cs1 = 0.f;

    while (live0 | live1) {
        if (live0) {
            unsigned rc = rec0;
            p0++;
            rec0 = sorted[p0 < N_EDGES_C ? p0 : (N_EDGES_C - 1)];  // seq prefetch
            float nv = bf2f((unsigned short)(rc & 0xffffu));
            unsigned hv = *(const unsigned*)&hb[(size_t)(rc >> 16) * FEAT + lane * 2];
            a00 += nv * lo16(hv);
            a01 += nv * hi16(hv);
            cs0 += nv;
            if (p0 >= bend0) {
                FLUSH(row0, j0, a00, a01, cs0);
                a00 = a01 = cs0 = 0.f;
                j0++; if (j0 < 8) bend0 = __shfl(bnds0, j0 + 1);
                while (j0 < 8 && p0 >= bend0) {
                    FLUSH(row0, j0, 0.f, 0.f, 0.f);
                    j0++; if (j0 < 8) bend0 = __shfl(bnds0, j0 + 1);
                }
                live0 = (j0 < 8);
            }
        }
        if (live1) {
            unsigned rc = rec1;
            p1++;
            rec1 = sorted[p1 < N_EDGES_C ? p1 : (N_EDGES_C - 1)];
            float nv = bf2f((unsigned short)(rc & 0xffffu));
            unsigned hv = *(const unsigned*)&hb[(size_t)(rc >> 16) * FEAT + lane * 2];
            a10 += nv * lo16(hv);
            a11 += nv * hi16(hv);
            cs1 += nv;
            if (p1 >= bend1) {
                FLUSH(row1, j1, a10, a11, cs1);
                a10 = a11 = cs1 = 0.f;
                j1++; if (j1 < 8) bend1 = __shfl(bnds1, j1 + 1);
                while (j1 < 8 && p1 >= bend1) {
                    FLUSH(row1, j1, 0.f, 0.f, 0.f);
                    j1++; if (j1 < 8) bend1 = __shfl(bnds1, j1 + 1);
                }
                live1 = (j1 < 8);
            }
        }
    }
#undef FLUSH
    __syncthreads();

    // ---- single MFMA pass: K=1024, wave w covers cols [w*16, w*16+16) ----
    f32x4 acc = (f32x4){0.f, 0.f, 0.f, 0.f};
    const unsigned short* wcol = wt + (size_t)(w * 16 + ln16) * KTOT + grp * 8;
#pragma unroll 8
    for (int ks = 0; ks < 32; ks++) {
        bf16x8 af = *(const bf16x8*)(At + ln16 * 2048 +
                                     ((ks * 64 + grp * 16) ^ ((ln16 & 7) << 4)));
        bf16x8 bf = *(const bf16x8*)(wcol + ks * 32);
        acc = __builtin_amdgcn_mfma_f32_16x16x32_bf16(af, bf, acc, 0, 0, 0);
    }

    // ---- epilogue: bias via csum + ReLU. D map: col=lane&15, row=(lane>>4)*4+reg
#pragma unroll
    for (int i = 0; i < 4; i++) {
        int rl = grp * 4 + i;
        int g  = node0 + rl;
        int col = w * 16 + ln16;
        float v = acc[i];
#pragma unroll
        for (int rr = 0; rr < NREL; rr++) v += csLds[rl][rr] * bias[rr * FEAT + col];
        out[(size_t)g * FEAT + col] = fmaxf(v, 0.f);
    }
}

extern "C" void kernel_launch(void* const* d_in, const int* in_sizes, int n_in,
                              void* d_out, int out_size, void* d_ws, size_t ws_size,
                              hipStream_t stream) {
    const float* h    = (const float*)d_in[0];
    const int*   src  = (const int*)d_in[1];
    const int*   dst  = (const int*)d_in[2];
    const int*   et   = (const int*)d_in[3];
    const float* norm = (const float*)d_in[4];
    const float* W    = (const float*)d_in[5];
    const float* b    = (const float*)d_in[6];
    float*       out  = (float*)d_out;

    if (ws_size < (size_t)WS_NEEDED) return;

    char* ws = (char*)d_ws;
    unsigned*       counts  = (unsigned*)(ws + WS_COUNTS);
    unsigned*       offsets = (unsigned*)(ws + WS_OFFSETS);
    unsigned char*  rank    = (unsigned char*)(ws + WS_RANK);
    unsigned*       bsum    = (unsigned*)(ws + WS_BSUM);
    unsigned*       boff    = (unsigned*)(ws + WS_BOFF);
    unsigned*       sorted  = (unsigned*)(ws + WS_SORTED);
    unsigned short* hb      = (unsigned short*)(ws + WS_HB);
    unsigned short* wt      = (unsigned short*)(ws + WS_WT);

    int nb = (NBUCKETS + 1023) / 1024;   // 391

    k_prep<<<3125 + 98 + 512, 256, 0, stream>>>(h, W, counts, hb, wt);
    k_hist<<<6250, 256, 0, stream>>>(dst, et, counts, rank);
    k_scan_a<<<nb, 1024, 0, stream>>>(counts, bsum);
    k_scan_b<<<1, 512, 0, stream>>>(bsum, boff, nb);
    k_scan_c<<<nb, 1024, 0, stream>>>(counts, boff, offsets);
    k_scatter<<<6250, 256, 0, stream>>>(src, dst, et, norm, offsets, rank, sorted);

    k_fused<<<N_NODES_C / TILE, 512, 0, stream>>>(sorted, offsets, hb, wt, b, out);
}

// Round 8
// 265.351 us; speedup vs baseline: 1.6471x; 1.1917x over previous
//
#include <hip/hip_runtime.h>

#define N_NODES_C   50000
#define N_EDGES_C   1600000
#define FEAT        128
#define NREL        8
#define NBUCKETS    400000
#define KTOT        1024
#define TILE        16                 // nodes per block; 50000 = 3125*16 exactly

// ---------------- workspace layout (bytes) ----------------
#define WS_COUNTS   0          // u32[100000] (u8x4 packed)     400,000
#define WS_OFFSETS  400000     // u32[400001] (+sentinel)     1,600,016
#define WS_RANK     2000016    // u8[1.6M]                    1,600,000
#define WS_BSUM     3600016    // u32[512]                        2,048
#define WS_BOFF     3602064    // u32[512]                        2,048
#define WS_SORTED   3604112    // u32[1.6M]                   6,400,000
#define WS_HB       10004112   // bf16[50000*128]            12,800,000
#define WS_WT       22804112   // bf16[128][1024]               262,144
#define WS_NEEDED   23066256

typedef __attribute__((ext_vector_type(8))) short bf16x8;
typedef __attribute__((ext_vector_type(4))) float f32x4;

__device__ __forceinline__ unsigned short f2bf(float f) {
    unsigned u = __float_as_uint(f);
    return (unsigned short)((u + 0x7fffu + ((u >> 16) & 1u)) >> 16);  // RNE
}
__device__ __forceinline__ float bf2f(unsigned short b) {
    return __uint_as_float((unsigned)b << 16);
}
__device__ __forceinline__ float lo16(unsigned u) { return __uint_as_float(u << 16); }
__device__ __forceinline__ float hi16(unsigned u) { return __uint_as_float(u & 0xffff0000u); }

// fused: cast h->bf16 | zero packed counts | build Wcat^T bf16 [n][r*128+k]
__global__ void k_prep(const float* __restrict__ h, const float* __restrict__ W,
                       unsigned* __restrict__ counts, unsigned short* __restrict__ hb,
                       unsigned short* __restrict__ wt) {
    int b = blockIdx.x, t = threadIdx.x;
    if (b < 3125) {                         // h cast: 6.4M elems, 8/thread
        int i = (b * 256 + t) * 8;
        float4 v0 = *(const float4*)&h[i];
        float4 v1 = *(const float4*)&h[i + 4];
        uint4 o;
        o.x = (unsigned)f2bf(v0.x) | ((unsigned)f2bf(v0.y) << 16);
        o.y = (unsigned)f2bf(v0.z) | ((unsigned)f2bf(v0.w) << 16);
        o.z = (unsigned)f2bf(v1.x) | ((unsigned)f2bf(v1.y) << 16);
        o.w = (unsigned)f2bf(v1.z) | ((unsigned)f2bf(v1.w) << 16);
        *(uint4*)&hb[i] = o;
    } else if (b < 3125 + 98) {             // zero 100000 u32 of packed counts
        int i = (b - 3125) * 256 + t;       // uint4 index
        if (i < 25000) ((uint4*)counts)[i] = make_uint4(0u, 0u, 0u, 0u);
    } else {                                // wt[n*1024 + rk] = W[rk*128 + n]
        int i = (b - 3223) * 256 + t;       // 0..131071
        int n = i >> 10, rk = i & 1023;
        wt[i] = f2bf(W[rk * FEAT + n]);
    }
}

// packed u8 histogram: 4 buckets per u32 word (bucket count << 255 w.h.p.)
__global__ void k_hist(const int* __restrict__ dst, const int* __restrict__ et,
                       unsigned* __restrict__ counts, unsigned char* __restrict__ rank) {
    int e = blockIdx.x * 256 + threadIdx.x;
    if (e < N_EDGES_C) {
        int key = dst[e] * NREL + et[e];
        int sh = 8 * (key & 3);
        unsigned old = atomicAdd(&counts[key >> 2], 1u << sh);
        rank[e] = (unsigned char)((old >> sh) & 0xffu);
    }
}

__global__ void k_scan_a(const unsigned* __restrict__ counts, unsigned* __restrict__ bsum) {
    __shared__ unsigned s[1024];
    int t = threadIdx.x;
    int i = blockIdx.x * 1024 + t;
    unsigned v = 0;
    if (i < NBUCKETS) v = (counts[i >> 2] >> (8 * (i & 3))) & 0xffu;
    s[t] = v;
    __syncthreads();
    for (int o = 512; o > 0; o >>= 1) {
        if (t < o) s[t] += s[t + o];
        __syncthreads();
    }
    if (t == 0) bsum[blockIdx.x] = s[0];
}

__global__ void k_scan_b(const unsigned* __restrict__ bsum, unsigned* __restrict__ boff, int nb) {
    __shared__ unsigned s[512];
    int t = threadIdx.x;
    unsigned v = (t < nb) ? bsum[t] : 0u;
    s[t] = v;
    __syncthreads();
    for (int o = 1; o < 512; o <<= 1) {
        unsigned u = (t >= o) ? s[t - o] : 0u;
        __syncthreads();
        s[t] += u;
        __syncthreads();
    }
    if (t < nb) boff[t] = s[t] - v;
}

__global__ void k_scan_c(const unsigned* __restrict__ counts, const unsigned* __restrict__ boff,
                         unsigned* __restrict__ offsets) {
    __shared__ unsigned s[1024];
    int t = threadIdx.x;
    int i = blockIdx.x * 1024 + t;
    unsigned v = 0;
    if (i < NBUCKETS) v = (counts[i >> 2] >> (8 * (i & 3))) & 0xffu;
    s[t] = v;
    __syncthreads();
    for (int o = 1; o < 1024; o <<= 1) {
        unsigned u = (t >= o) ? s[t - o] : 0u;
        __syncthreads();
        s[t] += u;
        __syncthreads();
    }
    if (i < NBUCKETS) offsets[i] = boff[blockIdx.x] + s[t] - v;
    if (i == NBUCKETS) offsets[i] = N_EDGES_C;   // sentinel
}

// atomic-free scatter of 4B records: (src<<16) | bf16(norm)
__global__ void k_scatter(const int* __restrict__ src, const int* __restrict__ dst,
                          const int* __restrict__ et, const float* __restrict__ norm,
                          const unsigned* __restrict__ offsets,
                          const unsigned char* __restrict__ rank,
                          unsigned* __restrict__ sorted) {
    int e = blockIdx.x * 256 + threadIdx.x;
    if (e < N_EDGES_C) {
        int key = dst[e] * NREL + et[e];
        unsigned pos = offsets[key] + (unsigned)rank[e];
        sorted[pos] = ((unsigned)src[e] << 16) | (unsigned)f2bf(norm[e]);
    }
}

// Fused aggregate+GEMM, TILE=16 nodes/block, 512 threads = 8 waves.
// Wave w owns rows 2w,2w+1 = ONE contiguous 16-bucket record stream.
// Batch-phase pipeline (8-deep): issue 8 independent row-gathers, then 8
// sequential record prefetches, THEN consume with bucket logic — no branch
// sits between load issues, so 8+ vmem ops stay in flight per wave.
// One barrier, then a single K=1024 MFMA pass (1 col-tile/wave, B from wt).
__global__ __launch_bounds__(512) void k_fused(const unsigned* __restrict__ sorted,
                                               const unsigned* __restrict__ offsets,
                                               const unsigned short* __restrict__ hb,
                                               const unsigned short* __restrict__ wt,
                                               const float* __restrict__ bias,
                                               float* __restrict__ out) {
    __shared__ char At[32768];            // [16 rows][1024 k] bf16, XOR-swizzled
    __shared__ float csLds[TILE][NREL];
    int t = threadIdx.x, w = t >> 6, lane = t & 63;
    int node0 = blockIdx.x * TILE;
    int grp = lane >> 4, ln16 = lane & 15;

    // 17 bucket boundaries (2 rows x 8 rels), lane-parallel
    int kbase = (node0 + 2 * w) * NREL;
    unsigned bnds = offsets[kbase + (lane <= 16 ? lane : 16)];
    unsigned pp   = __shfl(bnds, 0);
    unsigned send = __shfl(bnds, 16);
    int j = 0;
    unsigned bend = __shfl(bnds, 1);
    float a0 = 0.f, a1 = 0.f, cs = 0.f;

#define FLUSHJ(JJ, A0, A1, CS)                                                 \
    do {                                                                       \
        int row_ = 2 * w + ((JJ) >> 3);                                        \
        int jr_  = (JJ) & 7;                                                   \
        *(unsigned*)(At + row_ * 2048 +                                        \
                     ((jr_ * 256 + lane * 4) ^ ((row_ & 7) << 4))) =           \
            (unsigned)f2bf(A0) | ((unsigned)f2bf(A1) << 16);                   \
        if (lane == 0) csLds[row_][jr_] = (CS);                                \
    } while (0)

    unsigned rec[8];
#pragma unroll
    for (int u = 0; u < 8; u++) {
        unsigned q = pp + u;
        rec[u] = sorted[q < N_EDGES_C ? q : (N_EDGES_C - 1)];
    }

    while (pp < send) {
        // phase 1: 8 independent row-gathers (8 x 256B in flight)
        unsigned hv[8];
#pragma unroll
        for (int u = 0; u < 8; u++)
            hv[u] = *(const unsigned*)&hb[(size_t)(rec[u] >> 16) * FEAT + lane * 2];
        // phase 2: prefetch next batch of records (sequential lines)
        unsigned nrec[8];
#pragma unroll
        for (int u = 0; u < 8; u++) {
            unsigned q = pp + 8 + u;
            nrec[u] = sorted[q < N_EDGES_C ? q : (N_EDGES_C - 1)];
        }
        // phase 3: consume on already-loaded data (scalar bucket logic)
#pragma unroll
        for (int u = 0; u < 8; u++) {
            if (pp >= send) break;
            while (pp >= bend) {               // flush bucket j, advance (empties=0)
                FLUSHJ(j, a0, a1, cs);
                a0 = a1 = cs = 0.f;
                j++;
                bend = __shfl(bnds, j + 1 <= 16 ? j + 1 : 16);
            }
            float nv = bf2f((unsigned short)(rec[u] & 0xffffu));
            a0 += nv * lo16(hv[u]);
            a1 += nv * hi16(hv[u]);
            cs += nv;
            pp++;
        }
#pragma unroll
        for (int u = 0; u < 8; u++) rec[u] = nrec[u];
    }
    // trailing: flush current bucket, then zeros through bucket 15
    while (j < 16) {
        FLUSHJ(j, a0, a1, cs);
        a0 = a1 = cs = 0.f;
        j++;
    }
#undef FLUSHJ
    __syncthreads();

    // ---- single MFMA pass: K=1024, wave w covers cols [w*16, w*16+16) ----
    f32x4 acc = (f32x4){0.f, 0.f, 0.f, 0.f};
    const unsigned short* wcol = wt + (size_t)(w * 16 + ln16) * KTOT + grp * 8;
#pragma unroll 8
    for (int ks = 0; ks < 32; ks++) {
        bf16x8 af = *(const bf16x8*)(At + ln16 * 2048 +
                                     ((ks * 64 + grp * 16) ^ ((ln16 & 7) << 4)));
        bf16x8 bf = *(const bf16x8*)(wcol + ks * 32);
        acc = __builtin_amdgcn_mfma_f32_16x16x32_bf16(af, bf, acc, 0, 0, 0);
    }

    // ---- epilogue: bias via csum + ReLU. D map: col=lane&15, row=(lane>>4)*4+reg
#pragma unroll
    for (int i = 0; i < 4; i++) {
        int rl = grp * 4 + i;
        int g  = node0 + rl;
        int col = w * 16 + ln16;
        float v = acc[i];
#pragma unroll
        for (int rr = 0; rr < NREL; rr++) v += csLds[rl][rr] * bias[rr * FEAT + col];
        out[(size_t)g * FEAT + col] = fmaxf(v, 0.f);
    }
}

extern "C" void kernel_launch(void* const* d_in, const int* in_sizes, int n_in,
                              void* d_out, int out_size, void* d_ws, size_t ws_size,
                              hipStream_t stream) {
    const float* h    = (const float*)d_in[0];
    const int*   src  = (const int*)d_in[1];
    const int*   dst  = (const int*)d_in[2];
    const int*   et   = (const int*)d_in[3];
    const float* norm = (const float*)d_in[4];
    const float* W    = (const float*)d_in[5];
    const float* b    = (const float*)d_in[6];
    float*       out  = (float*)d_out;

    if (ws_size < (size_t)WS_NEEDED) return;

    char* ws = (char*)d_ws;
    unsigned*       counts  = (unsigned*)(ws + WS_COUNTS);
    unsigned*       offsets = (unsigned*)(ws + WS_OFFSETS);
    unsigned char*  rank    = (unsigned char*)(ws + WS_RANK);
    unsigned*       bsum    = (unsigned*)(ws + WS_BSUM);
    unsigned*       boff    = (unsigned*)(ws + WS_BOFF);
    unsigned*       sorted  = (unsigned*)(ws + WS_SORTED);
    unsigned short* hb      = (unsigned short*)(ws + WS_HB);
    unsigned short* wt      = (unsigned short*)(ws + WS_WT);

    int nb = (NBUCKETS + 1023) / 1024;   // 391

    k_prep<<<3125 + 98 + 512, 256, 0, stream>>>(h, W, counts, hb, wt);
    k_hist<<<6250, 256, 0, stream>>>(dst, et, counts, rank);
    k_scan_a<<<nb, 1024, 0, stream>>>(counts, bsum);
    k_scan_b<<<1, 512, 0, stream>>>(bsum, boff, nb);
    k_scan_c<<<nb, 1024, 0, stream>>>(counts, boff, offsets);
    k_scatter<<<6250, 256, 0, stream>>>(src, dst, et, norm, offsets, rank, sorted);

    k_fused<<<N_NODES_C / TILE, 512, 0, stream>>>(sorted, offsets, hb, wt, b, out);
}

// Round 9
// 262.627 us; speedup vs baseline: 1.6642x; 1.0104x over previous
//
#include <hip/hip_runtime.h>

#define N_NODES_C   50000
#define N_EDGES_C   1600000
#define FEAT        128
#define NREL        8
#define NBUCKETS    400000
#define KTOT        1024
#define TILE        16                 // nodes per block; 50000 = 3125*16 exactly

// ---------------- workspace layout (bytes) ----------------
#define WS_COUNTS   0          // u32[100000] (u8x4 packed)     400,000
#define WS_OFFSETS  400000     // u32[400001] (+sentinel)     1,600,016
#define WS_RANK     2000016    // u8[1.6M]                    1,600,000
#define WS_BSUM     3600016    // u32[512]                        2,048
#define WS_BOFF     3602064    // u32[512]                        2,048
#define WS_SORTED   3604112    // u32[1.6M]                   6,400,000
#define WS_HB       10004112   // bf16[50000*128]            12,800,000
#define WS_WT       22804112   // bf16[128][1024]               262,144
#define WS_NEEDED   23066256

typedef __attribute__((ext_vector_type(8))) short bf16x8;
typedef __attribute__((ext_vector_type(4))) float f32x4;

__device__ __forceinline__ unsigned short f2bf(float f) {
    unsigned u = __float_as_uint(f);
    return (unsigned short)((u + 0x7fffu + ((u >> 16) & 1u)) >> 16);  // RNE
}
__device__ __forceinline__ float bf2f(unsigned short b) {
    return __uint_as_float((unsigned)b << 16);
}
__device__ __forceinline__ float lo16(unsigned u) { return __uint_as_float(u << 16); }
__device__ __forceinline__ float hi16(unsigned u) { return __uint_as_float(u & 0xffff0000u); }

// zero packed counts (must precede hist)
__global__ void k_zero(unsigned* __restrict__ counts) {
    int i = blockIdx.x * 256 + threadIdx.x;
    if (i < 25000) ((uint4*)counts)[i] = make_uint4(0u, 0u, 0u, 0u);
}

// hist (blocks 0..6249) | h->bf16 cast (6250..9374) | Wcat^T build (9375..9886)
__global__ void k_histprep(const int* __restrict__ dst, const int* __restrict__ et,
                           unsigned* __restrict__ counts, unsigned char* __restrict__ rank,
                           const float* __restrict__ h, unsigned short* __restrict__ hb,
                           const float* __restrict__ W, unsigned short* __restrict__ wt) {
    int b = blockIdx.x, t = threadIdx.x;
    if (b < 6250) {
        int e = b * 256 + t;
        if (e < N_EDGES_C) {
            int key = dst[e] * NREL + et[e];
            int sh = 8 * (key & 3);
            unsigned old = atomicAdd(&counts[key >> 2], 1u << sh);
            rank[e] = (unsigned char)((old >> sh) & 0xffu);
        }
    } else if (b < 6250 + 3125) {
        int i = ((b - 6250) * 256 + t) * 8;
        float4 v0 = *(const float4*)&h[i];
        float4 v1 = *(const float4*)&h[i + 4];
        uint4 o;
        o.x = (unsigned)f2bf(v0.x) | ((unsigned)f2bf(v0.y) << 16);
        o.y = (unsigned)f2bf(v0.z) | ((unsigned)f2bf(v0.w) << 16);
        o.z = (unsigned)f2bf(v1.x) | ((unsigned)f2bf(v1.y) << 16);
        o.w = (unsigned)f2bf(v1.z) | ((unsigned)f2bf(v1.w) << 16);
        *(uint4*)&hb[i] = o;
    } else {
        int i = (b - 9375) * 256 + t;       // 0..131071
        int n = i >> 10, rk = i & 1023;
        wt[i] = f2bf(W[rk * FEAT + n]);     // wt[n*1024 + rk]
    }
}

__global__ void k_scan_a(const unsigned* __restrict__ counts, unsigned* __restrict__ bsum) {
    __shared__ unsigned s[1024];
    int t = threadIdx.x;
    int i = blockIdx.x * 1024 + t;
    unsigned v = 0;
    if (i < NBUCKETS) v = (counts[i >> 2] >> (8 * (i & 3))) & 0xffu;
    s[t] = v;
    __syncthreads();
    for (int o = 512; o > 0; o >>= 1) {
        if (t < o) s[t] += s[t + o];
        __syncthreads();
    }
    if (t == 0) bsum[blockIdx.x] = s[0];
}

__global__ void k_scan_b(const unsigned* __restrict__ bsum, unsigned* __restrict__ boff, int nb) {
    __shared__ unsigned s[512];
    int t = threadIdx.x;
    unsigned v = (t < nb) ? bsum[t] : 0u;
    s[t] = v;
    __syncthreads();
    for (int o = 1; o < 512; o <<= 1) {
        unsigned u = (t >= o) ? s[t - o] : 0u;
        __syncthreads();
        s[t] += u;
        __syncthreads();
    }
    if (t < nb) boff[t] = s[t] - v;
}

__global__ void k_scan_c(const unsigned* __restrict__ counts, const unsigned* __restrict__ boff,
                         unsigned* __restrict__ offsets) {
    __shared__ unsigned s[1024];
    int t = threadIdx.x;
    int i = blockIdx.x * 1024 + t;
    unsigned v = 0;
    if (i < NBUCKETS) v = (counts[i >> 2] >> (8 * (i & 3))) & 0xffu;
    s[t] = v;
    __syncthreads();
    for (int o = 1; o < 1024; o <<= 1) {
        unsigned u = (t >= o) ? s[t - o] : 0u;
        __syncthreads();
        s[t] += u;
        __syncthreads();
    }
    if (i < NBUCKETS) offsets[i] = boff[blockIdx.x] + s[t] - v;
    if (i == NBUCKETS) offsets[i] = N_EDGES_C;   // sentinel
}

// atomic-free scatter of 4B records: (src<<16) | bf16(norm)
__global__ void k_scatter(const int* __restrict__ src, const int* __restrict__ dst,
                          const int* __restrict__ et, const float* __restrict__ norm,
                          const unsigned* __restrict__ offsets,
                          const unsigned char* __restrict__ rank,
                          unsigned* __restrict__ sorted) {
    int e = blockIdx.x * 256 + threadIdx.x;
    if (e < N_EDGES_C) {
        int key = dst[e] * NREL + et[e];
        unsigned pos = offsets[key] + (unsigned)rank[e];
        sorted[pos] = ((unsigned)src[e] << 16) | (unsigned)f2bf(norm[e]);
    }
}

// Fused aggregate+GEMM, TILE=16 nodes/block, 512 threads = 8 waves.
// Wave w owns rows 2w,2w+1 = ONE contiguous 16-bucket record stream.
// Window pipeline: ONE wave-parallel load fetches 64 records; each record is
// broadcast via v_readlane -> SGPR, so its row address is SALU-computed and
// the gather is global_load_dword(v_laneoff, s[row]); nv stays scalar and
// feeds v_fmac as the SGPR operand. Per-record VALU ~6 (was ~10).
// One barrier, then a single K=1024 MFMA pass (1 col-tile/wave, B from wt).
__global__ __launch_bounds__(512) void k_fused(const unsigned* __restrict__ sorted,
                                               const unsigned* __restrict__ offsets,
                                               const unsigned short* __restrict__ hb,
                                               const unsigned short* __restrict__ wt,
                                               const float* __restrict__ bias,
                                               float* __restrict__ out) {
    __shared__ char At[32768];            // [16 rows][1024 k] bf16, XOR-swizzled
    __shared__ float csLds[TILE][NREL];
    int t = threadIdx.x, w = t >> 6, lane = t & 63;
    int node0 = blockIdx.x * TILE;
    int grp = lane >> 4, ln16 = lane & 15;

    // 17 bucket boundaries (2 rows x 8 rels), lane-parallel
    int kbase = (node0 + 2 * w) * NREL;
    unsigned bnds = offsets[kbase + (lane <= 16 ? lane : 16)];
    unsigned pp   = __shfl(bnds, 0);
    unsigned send = __shfl(bnds, 16);
    int j = 0;
    unsigned bend = (unsigned)__builtin_amdgcn_readlane((int)bnds, 1);
    float a0 = 0.f, a1 = 0.f, cs = 0.f;

#define FLUSHJ(JJ, A0, A1, CS)                                                 \
    do {                                                                       \
        int row_ = 2 * w + ((JJ) >> 3);                                        \
        int jr_  = (JJ) & 7;                                                   \
        *(unsigned*)(At + row_ * 2048 +                                        \
                     ((jr_ * 256 + lane * 4) ^ ((row_ & 7) << 4))) =           \
            (unsigned)f2bf(A0) | ((unsigned)f2bf(A1) << 16);                   \
        if (lane == 0) csLds[row_][jr_] = (CS);                                \
    } while (0)

    {
        unsigned q0 = pp + lane;
        unsigned recv = sorted[q0 < N_EDGES_C ? q0 : (N_EDGES_C - 1)];
        unsigned wstart = pp;
        while (wstart < send) {
            unsigned qn = wstart + 64 + lane;
            unsigned recv_n = sorted[qn < N_EDGES_C ? qn : (N_EDGES_C - 1)];
#pragma unroll 1
            for (int b = 0; b < 8; b++) {
                // gather phase: 8 speculative row-loads, scalar base addresses
                unsigned hv[8];
                float nvv[8];
#pragma unroll
                for (int u = 0; u < 8; u++) {
                    unsigned ru = (unsigned)__builtin_amdgcn_readlane((int)recv, b * 8 + u);
                    nvv[u] = __uint_as_float((ru & 0xffffu) << 16);
                    const unsigned short* rp = hb + (size_t)(ru >> 16) * FEAT;
                    hv[u] = *(const unsigned*)(rp + lane * 2);
                }
                // consume phase: scalar bucket logic on loaded data
#pragma unroll
                for (int u = 0; u < 8; u++) {
                    unsigned gpos = wstart + (unsigned)(b * 8 + u);
                    if (gpos >= send) goto stream_done;
                    while (gpos >= bend) {       // flush bucket j, advance
                        FLUSHJ(j, a0, a1, cs);
                        a0 = a1 = cs = 0.f;
                        j++;
                        bend = (unsigned)__builtin_amdgcn_readlane(
                            (int)bnds, j < 16 ? j + 1 : 16);
                    }
                    a0 += nvv[u] * lo16(hv[u]);
                    a1 += nvv[u] * hi16(hv[u]);
                    cs += nvv[u];
                }
            }
            wstart += 64;
            recv = recv_n;
        }
    stream_done:;
    }
    // trailing: flush current bucket, then zeros through bucket 15
    while (j < 16) {
        FLUSHJ(j, a0, a1, cs);
        a0 = a1 = cs = 0.f;
        j++;
    }
#undef FLUSHJ
    __syncthreads();

    // ---- single MFMA pass: K=1024, wave w covers cols [w*16, w*16+16) ----
    f32x4 acc = (f32x4){0.f, 0.f, 0.f, 0.f};
    const unsigned short* wcol = wt + (size_t)(w * 16 + ln16) * KTOT + grp * 8;
#pragma unroll 8
    for (int ks = 0; ks < 32; ks++) {
        bf16x8 af = *(const bf16x8*)(At + ln16 * 2048 +
                                     ((ks * 64 + grp * 16) ^ ((ln16 & 7) << 4)));
        bf16x8 bf = *(const bf16x8*)(wcol + ks * 32);
        acc = __builtin_amdgcn_mfma_f32_16x16x32_bf16(af, bf, acc, 0, 0, 0);
    }

    // ---- epilogue: bias via csum + ReLU. D map: col=lane&15, row=(lane>>4)*4+reg
#pragma unroll
    for (int i = 0; i < 4; i++) {
        int rl = grp * 4 + i;
        int g  = node0 + rl;
        int col = w * 16 + ln16;
        float v = acc[i];
#pragma unroll
        for (int rr = 0; rr < NREL; rr++) v += csLds[rl][rr] * bias[rr * FEAT + col];
        out[(size_t)g * FEAT + col] = fmaxf(v, 0.f);
    }
}

extern "C" void kernel_launch(void* const* d_in, const int* in_sizes, int n_in,
                              void* d_out, int out_size, void* d_ws, size_t ws_size,
                              hipStream_t stream) {
    const float* h    = (const float*)d_in[0];
    const int*   src  = (const int*)d_in[1];
    const int*   dst  = (const int*)d_in[2];
    const int*   et   = (const int*)d_in[3];
    const float* norm = (const float*)d_in[4];
    const float* W    = (const float*)d_in[5];
    const float* b    = (const float*)d_in[6];
    float*       out  = (float*)d_out;

    if (ws_size < (size_t)WS_NEEDED) return;

    char* ws = (char*)d_ws;
    unsigned*       counts  = (unsigned*)(ws + WS_COUNTS);
    unsigned*       offsets = (unsigned*)(ws + WS_OFFSETS);
    unsigned char*  rank    = (unsigned char*)(ws + WS_RANK);
    unsigned*       bsum    = (unsigned*)(ws + WS_BSUM);
    unsigned*       boff    = (unsigned*)(ws + WS_BOFF);
    unsigned*       sorted  = (unsigned*)(ws + WS_SORTED);
    unsigned short* hb      = (unsigned short*)(ws + WS_HB);
    unsigned short* wt      = (unsigned short*)(ws + WS_WT);

    int nb = (NBUCKETS + 1023) / 1024;   // 391

    k_zero<<<98, 256, 0, stream>>>(counts);
    k_histprep<<<6250 + 3125 + 512, 256, 0, stream>>>(dst, et, counts, rank,
                                                      h, hb, W, wt);
    k_scan_a<<<nb, 1024, 0, stream>>>(counts, bsum);
    k_scan_b<<<1, 512, 0, stream>>>(bsum, boff, nb);
    k_scan_c<<<nb, 1024, 0, stream>>>(counts, boff, offsets);
    k_scatter<<<6250, 256, 0, stream>>>(src, dst, et, norm, offsets, rank, sorted);

    k_fused<<<N_NODES_C / TILE, 512, 0, stream>>>(sorted, offsets, hb, wt, b, out);
}